// Round 3
// baseline (261.871 us; speedup 1.0000x reference)
//
#include <hip/hip_runtime.h>
#include <math.h>

// DFT_10316511445664, folded direct DFT as a tiny GEMM.
// Real input x[100]; outputs bins m=50..99: Re[m], Im[m], each scaled 1/100.
//   Re[m] = sum_{n=0..50} e~[n] * cos(2pi*m*n/100) / 100,  e~[n]=x[n]+x[100-n] (n=1..49), e~[0]=x[0], e~[50]=x[50]
//   Im[m] = -sum_{n=1..49} o[n]  * sin(2pi*m*n/100) / 100,  o[n]=x[n]-x[100-n]
// Folded weight table W2[100][52]: rows 0..49 = cos rows (Re), 50..99 = -sin rows (Im),
// with zero weights at masked positions -> branch-free hot loop.
// Block = 64 samples, 4 waves; wave w owns 25 output cols; lane = sample.
// e/o tile + W2 both in LDS; W2 read via uniform-address ds_read_b128 (HW broadcast).

#define NFFT  100
#define CROP  50
#define BLOCK 256
#define TM    64
#define EOS   108     // e/o row stride in floats (16B aligned)
#define OSTR  101     // out-staging stride (odd -> conflict-free scalar writes)
#define WROW  52      // W2 row length (16B aligned, covers taps 0..50)
#define LOGPZ_CONST -91.893853320467274f

__device__ float g_W2[NFFT * WROW];

__global__ void init_w_kernel() {
    int idx = blockIdx.x * blockDim.x + threadIdx.x;
    if (idx < NFFT * WROW) {
        int j = idx / WROW;          // 0..49: Re rows (bin 50+j); 50..99: Im rows (bin j)
        int n = idx - j * WROW;      // tap 0..51
        int bin = (j < CROP) ? (CROP + j) : j;
        int t = (bin * n) % NFFT;
        float ang = (float)t * 0.06283185307179586477f; // 2*pi/100
        float v = 0.0f;
        if (j < CROP) {
            if (n <= 50) v = cosf(ang) * 0.01f;
        } else {
            if (n >= 1 && n <= 49) v = -sinf(ang) * 0.01f;
        }
        g_W2[idx] = v;
    }
}

__global__ __launch_bounds__(BLOCK) void dft_kernel(const float* __restrict__ x,
                                                    float* __restrict__ out,
                                                    int B) {
    __shared__ float eo[TM * EOS];          // 27648 B; reused for out staging (stride 101)
    __shared__ float wlds[NFFT * WROW];     // 20800 B
    __shared__ float p2[4][TM];

    const int tid  = threadIdx.x;
    const int lane = tid & 63;
    const int wv   = tid >> 6;
    const size_t base = (size_t)blockIdx.x * TM * NFFT;
    const float* __restrict__ src = x + base;

    // stage W2 -> LDS (L3-resident source, cheap)
    for (int i = tid; i < NFFT * WROW; i += BLOCK) wlds[i] = g_W2[i];

    // build e~/o tile directly from global (mirror read is an L2 hit)
#pragma unroll
    for (int i = 0; i < 13; ++i) {
        int e2 = tid + i * BLOCK;            // 0..3327 over 64 rows x 52 slots
        int rr = e2 / WROW;
        int cc = e2 - rr * WROW;
        float v1 = (cc <= 50) ? src[rr * NFFT + cc] : 0.0f;
        float v2 = (cc >= 1 && cc <= 49) ? src[rr * NFFT + NFFT - cc] : 0.0f;
        eo[rr * EOS + cc]        = v1 + v2;  // e~ (garbage at cc=0/50 masked by W=0? no: e~ valid there)
        eo[rr * EOS + WROW + cc] = v1 - v2;  // o  (garbage at cc=0/50 masked by zero sin weights)
    }
    __syncthreads();

    // hot loop: 25 accumulators, 13 float4 chunks, W via uniform-address broadcast
    const float* __restrict__ wbase = wlds + wv * 25 * WROW;           // wv*25 in 0,25,50,75
    const float* __restrict__ xrow  = eo + lane * EOS + ((wv >= 2) ? WROW : 0);

    float acc[25];
#pragma unroll
    for (int j = 0; j < 25; ++j) acc[j] = 0.0f;

    for (int kc = 0; kc < 13; ++kc) {
        float4 xv = *reinterpret_cast<const float4*>(xrow + kc * 4);   // lane-varying
#pragma unroll
        for (int j = 0; j < 25; ++j) {
            float4 w4 = *reinterpret_cast<const float4*>(wbase + j * WROW + kc * 4); // broadcast
            acc[j] = fmaf(xv.x, w4.x, acc[j]);
            acc[j] = fmaf(xv.y, w4.y, acc[j]);
            acc[j] = fmaf(xv.z, w4.z, acc[j]);
            acc[j] = fmaf(xv.w, w4.w, acc[j]);
        }
    }

    float s2 = 0.0f;
#pragma unroll
    for (int j = 0; j < 25; ++j) s2 = fmaf(acc[j], acc[j], s2);
    p2[wv][lane] = s2;

    __syncthreads();    // everyone done reading eo

    // out staging at odd stride -> conflict-free
#pragma unroll
    for (int j = 0; j < 25; ++j) eo[lane * OSTR + wv * 25 + j] = acc[j];
    __syncthreads();

    float* __restrict__ dst = out + base;
#pragma unroll
    for (int i = 0; i < 25; ++i) {
        int e  = tid + i * BLOCK;
        int rr = e / NFFT;
        int cc = e - rr * NFFT;
        dst[e] = eo[rr * OSTR + cc];
    }

    if (wv == 0) {
        float t = p2[0][lane] + p2[1][lane] + p2[2][lane] + p2[3][lane];
        out[(size_t)B * NFFT + blockIdx.x * TM + lane] = fmaf(t, -0.5f, LOGPZ_CONST);
    }
}

extern "C" void kernel_launch(void* const* d_in, const int* in_sizes, int n_in,
                              void* d_out, int out_size, void* d_ws, size_t ws_size,
                              hipStream_t stream) {
    const float* x = (const float*)d_in[0];
    float* out = (float*)d_out;
    const int B = in_sizes[0] / NFFT;   // 262144

    hipLaunchKernelGGL(init_w_kernel, dim3((NFFT * WROW + BLOCK - 1) / BLOCK),
                       dim3(BLOCK), 0, stream);
    hipLaunchKernelGGL(dft_kernel, dim3(B / TM), dim3(BLOCK), 0, stream, x, out, B);
}

// Round 5
// 216.498 us; speedup vs baseline: 1.2096x; 1.2096x over previous
//
#include <hip/hip_runtime.h>
#include <hip/hip_bf16.h>
#include <math.h>

// DFT_10316511445664 via bf16 MFMA GEMM.
// OUT[B,100] = X[B,100] . W^T with W[j][k]:
//   j<50:  cos(2pi*(50+j)*k/100)/100   (Re of bins 50..99)
//   j>=50: -sin(2pi*j*k/100)/100       (Im of bin j)
// plus log_pz[s] = -0.5*sum_j OUT[s][j]^2 - 50*log(2pi).
//
// mfma_f32_16x16x32_bf16. Block = 64 samples, 4 waves; wave owns a 16-row
// M-tile; 7 N-tiles (N padded 112) x 4 K-groups (K padded 128) = 28 MFMAs.
// A-frags loaded straight from global (8 contiguous f32 -> bf16, tail zeroed
// in-register). B-frags from a zero-padded bf16 W table [112][128] (28 KB,
// L1-resident). C staged through LDS (stride 108 -> 2-way banks = free) for
// coalesced stores; log_pz via shfl-xor reduction across 16-lane col groups.

#define NFFT  100
#define CROP  50
#define BLOCK 256
#define TM    64
#define WN    112   // padded N
#define WK    128   // padded K
#define CSTR  108   // LDS C-stage row stride (floats); 4*108 % 32 == 16 -> 2-way
#define LOGPZ_CONST -91.893853320467274f

typedef short  bf16x8 __attribute__((ext_vector_type(8)));
typedef float  f32x4  __attribute__((ext_vector_type(4)));

__device__ unsigned short g_Wbf[WN * WK];

static __device__ inline short f2b(float f) {
    __hip_bfloat16 h = __float2bfloat16(f);
    return *reinterpret_cast<short*>(&h);
}

__global__ void init_w_kernel() {
    int idx = blockIdx.x * blockDim.x + threadIdx.x;
    if (idx < WN * WK) {
        int j = idx / WK;
        int k = idx - j * WK;
        float v = 0.0f;
        if (j < NFFT && k < NFFT) {
            int bin = (j < CROP) ? (CROP + j) : j;
            int t = (bin * k) % NFFT;
            float ang = (float)t * 0.06283185307179586477f; // 2*pi/100
            v = ((j < CROP) ? cosf(ang) : -sinf(ang)) * 0.01f;
        }
        g_Wbf[idx] = (unsigned short)f2b(v);
    }
}

__global__ __launch_bounds__(BLOCK) void dft_kernel(const float* __restrict__ x,
                                                    float* __restrict__ out,
                                                    int B) {
    __shared__ float cst[TM * CSTR];   // C staging
    __shared__ float p2[TM];           // per-row sum of squares

    const int tid  = threadIdx.x;
    const int lane = tid & 63;
    const int wv   = tid >> 6;          // wave -> M-tile
    const int lr   = lane & 15;         // row-within-tile (A) / col (B,C)
    const int kb   = lane >> 4;         // k-block 0..3

    const int rbase = blockIdx.x * TM + wv * 16 + lr;   // this lane's sample row
    const float* __restrict__ xr = x + (size_t)rbase * NFFT;

    // ---- A fragments: 8 contiguous f32 -> bf16, K padded with zeros ----
    bf16x8 afr[4];
#pragma unroll
    for (int kg = 0; kg < 3; ++kg) {
        const float4* p = reinterpret_cast<const float4*>(xr + kg * 32 + kb * 8);
        float4 u0 = p[0];
        float4 u1 = p[1];
        bf16x8 a;
        a[0] = f2b(u0.x); a[1] = f2b(u0.y); a[2] = f2b(u0.z); a[3] = f2b(u0.w);
        a[4] = f2b(u1.x); a[5] = f2b(u1.y); a[6] = f2b(u1.z); a[7] = f2b(u1.w);
        afr[kg] = a;
    }
    {
        // kg=3 covers k=96..127; only k=96..99 exist (kb==0, first 4 elems)
        float4 u = make_float4(0.f, 0.f, 0.f, 0.f);
        if (kb == 0) u = *reinterpret_cast<const float4*>(xr + 96);
        bf16x8 a;
        a[0] = f2b(u.x); a[1] = f2b(u.y); a[2] = f2b(u.z); a[3] = f2b(u.w);
        a[4] = 0; a[5] = 0; a[6] = 0; a[7] = 0;
        afr[3] = a;
    }

    // ---- GEMM: 7 N-tiles x 4 K-groups ----
    const unsigned short* __restrict__ W = g_Wbf;
    f32x4 acc[7];
#pragma unroll
    for (int nt = 0; nt < 7; ++nt) acc[nt] = (f32x4){0.f, 0.f, 0.f, 0.f};

#pragma unroll
    for (int nt = 0; nt < 7; ++nt) {
        const unsigned short* wrow = W + (size_t)(nt * 16 + lr) * WK + kb * 8;
#pragma unroll
        for (int kg = 0; kg < 4; ++kg) {
            bf16x8 bfr = *reinterpret_cast<const bf16x8*>(wrow + kg * 32);
            acc[nt] = __builtin_amdgcn_mfma_f32_16x16x32_bf16(afr[kg], bfr, acc[nt], 0, 0, 0);
        }
    }

    // ---- C -> LDS (rows = samples), partial sum of squares ----
    float s2[4] = {0.f, 0.f, 0.f, 0.f};
#pragma unroll
    for (int nt = 0; nt < 7; ++nt) {
        int col = nt * 16 + lr;
        if (col < NFFT) {
#pragma unroll
            for (int i = 0; i < 4; ++i) {
                float v = acc[nt][i];
                cst[(wv * 16 + kb * 4 + i) * CSTR + col] = v;
                s2[i] = fmaf(v, v, s2[i]);
            }
        }
    }

    // reduce across the 16 lanes sharing kb (cols of one row)
#pragma unroll
    for (int i = 0; i < 4; ++i) {
        float t = s2[i];
        t += __shfl_xor(t, 1, 64);
        t += __shfl_xor(t, 2, 64);
        t += __shfl_xor(t, 4, 64);
        t += __shfl_xor(t, 8, 64);
        if (lr == 0) p2[wv * 16 + kb * 4 + i] = t;
    }

    __syncthreads();

    // ---- coalesced store ----
    float* __restrict__ dst = out + (size_t)blockIdx.x * TM * NFFT;
#pragma unroll
    for (int i = 0; i < 25; ++i) {
        int e  = tid + i * BLOCK;       // 0..6399
        int rr = e / NFFT;
        int cc = e - rr * NFFT;
        dst[e] = cst[rr * CSTR + cc];
    }
    if (tid < TM) {
        out[(size_t)B * NFFT + blockIdx.x * TM + tid] =
            fmaf(p2[tid], -0.5f, LOGPZ_CONST);
    }
}

extern "C" void kernel_launch(void* const* d_in, const int* in_sizes, int n_in,
                              void* d_out, int out_size, void* d_ws, size_t ws_size,
                              hipStream_t stream) {
    const float* x = (const float*)d_in[0];
    float* out = (float*)d_out;
    const int B = in_sizes[0] / NFFT;   // 262144

    hipLaunchKernelGGL(init_w_kernel, dim3((WN * WK + BLOCK - 1) / BLOCK),
                       dim3(BLOCK), 0, stream);
    hipLaunchKernelGGL(dft_kernel, dim3(B / TM), dim3(BLOCK), 0, stream, x, out, B);
}

// Round 6
// 200.509 us; speedup vs baseline: 1.3060x; 1.0797x over previous
//
#include <hip/hip_runtime.h>
#include <hip/hip_bf16.h>
#include <math.h>

// DFT_10316511445664 via bf16 MFMA GEMM, software-pipelined.
// OUT[B,100] = X[B,100] . W^T with W[j][k]:
//   j<50:  cos(2pi*(50+j)*k/100)/100   (Re of bins 50..99)
//   j>=50: -sin(2pi*j*k/100)/100       (Im of bin j)
// plus log_pz[s] = -0.5*sum_j OUT[s][j]^2 - 50*log(2pi).
//
// Block = 256 thr (4 waves); block processes T=4 tiles of 64 samples with
// 1-deep register prefetch (loads for tile t+1 issued under tile t's
// MFMA+epilogue). Wave owns a 16-row M-tile; 7 N-tiles x 4 K-groups = 28
// mfma_f32_16x16x32_bf16 per tile. B-frags from a zero-padded bf16 W table
// [112][128] (28 KB, L1-resident; zero K/N padding makes A-tail garbage
// harmless). NO barriers: each wave stages C in a private LDS strip and
// stores its own 16 rows coalesced; log_pz finished in-wave via shfl_xor.

#define NFFT  100
#define CROP  50
#define BLOCK 256
#define TM    64
#define T     4     // tiles per block
#define WN    112   // padded N
#define WK    128   // padded K
#define CSTR  108   // C-stage row stride (floats): 4*108 % 32 = 16 -> 2-way (free)
#define LOGPZ_CONST -91.893853320467274f

typedef short  bf16x8 __attribute__((ext_vector_type(8)));
typedef float  f32x4  __attribute__((ext_vector_type(4)));

__device__ unsigned short g_Wbf[WN * WK];

static __device__ inline short f2b(float f) {
    __hip_bfloat16 h = __float2bfloat16(f);
    return *reinterpret_cast<short*>(&h);
}

__global__ void init_w_kernel() {
    int idx = blockIdx.x * blockDim.x + threadIdx.x;
    if (idx < WN * WK) {
        int j = idx / WK;
        int k = idx - j * WK;
        float v = 0.0f;
        if (j < NFFT && k < NFFT) {
            int bin = (j < CROP) ? (CROP + j) : j;
            int t = (bin * k) % NFFT;
            float ang = (float)t * 0.06283185307179586477f; // 2*pi/100
            v = ((j < CROP) ? cosf(ang) : -sinf(ang)) * 0.01f;
        }
        g_Wbf[idx] = (unsigned short)f2b(v);
    }
}

__global__ __launch_bounds__(BLOCK) void dft_kernel(const float* __restrict__ x,
                                                    float* __restrict__ out,
                                                    int B) {
    __shared__ float cst[TM * CSTR];   // 4 disjoint per-wave strips, no barriers

    const int tid  = threadIdx.x;
    const int lane = tid & 63;
    const int wv   = tid >> 6;          // wave -> 16-row M-tile strip
    const int lr   = lane & 15;         // row-in-tile (A) / col (B,C)
    const int kb   = lane >> 4;         // k-block 0..3

    const int rowInBlk = wv * 16 + lr;                 // 0..63
    const size_t blkBase = (size_t)blockIdx.x * (TM * T);
    const unsigned short* __restrict__ W = g_Wbf;

    float4 ld[7];
    bf16x8 afr[4];

    // ---- prologue: issue loads for tile 0 ----
    {
        const float* __restrict__ xr = x + (blkBase + rowInBlk) * NFFT;
#pragma unroll
        for (int kg = 0; kg < 3; ++kg) {
            const float4* p = reinterpret_cast<const float4*>(xr + kg * 32 + kb * 8);
            ld[2 * kg]     = p[0];
            ld[2 * kg + 1] = p[1];
        }
        ld[6] = *reinterpret_cast<const float4*>(xr + 96);
    }

    for (int t = 0; t < T; ++t) {
        // ---- convert arrived loads -> bf16 A-fragments ----
#pragma unroll
        for (int kg = 0; kg < 3; ++kg) {
            float4 u0 = ld[2 * kg], u1 = ld[2 * kg + 1];
            bf16x8 a;
            a[0] = f2b(u0.x); a[1] = f2b(u0.y); a[2] = f2b(u0.z); a[3] = f2b(u0.w);
            a[4] = f2b(u1.x); a[5] = f2b(u1.y); a[6] = f2b(u1.z); a[7] = f2b(u1.w);
            afr[kg] = a;
        }
        {
            // kg=3: k=96..127. Only kb==0's first 4 slots are real (k=96..99);
            // everything else multiplies zero-padded W rows/cols -> harmless.
            float4 u = ld[6];
            bf16x8 a;
            a[0] = f2b(u.x); a[1] = f2b(u.y); a[2] = f2b(u.z); a[3] = f2b(u.w);
            a[4] = 0; a[5] = 0; a[6] = 0; a[7] = 0;
            afr[3] = a;
        }

        // ---- prefetch tile t+1 (hidden under MFMA + epilogue) ----
        if (t + 1 < T) {
            const float* __restrict__ xr =
                x + (blkBase + (size_t)(t + 1) * TM + rowInBlk) * NFFT;
#pragma unroll
            for (int kg = 0; kg < 3; ++kg) {
                const float4* p = reinterpret_cast<const float4*>(xr + kg * 32 + kb * 8);
                ld[2 * kg]     = p[0];
                ld[2 * kg + 1] = p[1];
            }
            ld[6] = *reinterpret_cast<const float4*>(xr + 96);
        }

        // ---- GEMM: 7 N-tiles x 4 K-groups ----
        f32x4 acc[7];
#pragma unroll
        for (int nt = 0; nt < 7; ++nt) acc[nt] = (f32x4){0.f, 0.f, 0.f, 0.f};
#pragma unroll
        for (int nt = 0; nt < 7; ++nt) {
            const unsigned short* wrow = W + (size_t)(nt * 16 + lr) * WK + kb * 8;
#pragma unroll
            for (int kg = 0; kg < 4; ++kg) {
                bf16x8 bfr = *reinterpret_cast<const bf16x8*>(wrow + kg * 32);
                acc[nt] = __builtin_amdgcn_mfma_f32_16x16x32_bf16(afr[kg], bfr, acc[nt], 0, 0, 0);
            }
        }

        // ---- epilogue (wave-private, no barriers) ----
        float s2[4] = {0.f, 0.f, 0.f, 0.f};
#pragma unroll
        for (int nt = 0; nt < 7; ++nt) {
            int col = nt * 16 + lr;
            if (col < NFFT) {
#pragma unroll
                for (int i = 0; i < 4; ++i) {
                    float v = acc[nt][i];
                    cst[(wv * 16 + kb * 4 + i) * CSTR + col] = v;
                    s2[i] = fmaf(v, v, s2[i]);
                }
            }
        }

        const size_t tileBase = blkBase + (size_t)t * TM;

        // log_pz: reduce across the 16 lanes of each column group, store direct
#pragma unroll
        for (int i = 0; i < 4; ++i) {
            float r = s2[i];
            r += __shfl_xor(r, 1, 64);
            r += __shfl_xor(r, 2, 64);
            r += __shfl_xor(r, 4, 64);
            r += __shfl_xor(r, 8, 64);
            if (lr == 0) {
                out[(size_t)B * NFFT + tileBase + wv * 16 + kb * 4 + i] =
                    fmaf(r, -0.5f, LOGPZ_CONST);
            }
        }

        // coalesced store of this wave's 16 rows (1600 floats)
        const float* __restrict__ csrc = cst + wv * 16 * CSTR;
        float* __restrict__ dstw = out + (tileBase + wv * 16) * NFFT;
#pragma unroll
        for (int i = 0; i < 25; ++i) {
            int e  = lane + i * 64;     // 0..1599
            int rr = e / NFFT;
            int cc = e - rr * NFFT;
            dstw[e] = csrc[rr * CSTR + cc];
        }
    }
}

extern "C" void kernel_launch(void* const* d_in, const int* in_sizes, int n_in,
                              void* d_out, int out_size, void* d_ws, size_t ws_size,
                              hipStream_t stream) {
    const float* x = (const float*)d_in[0];
    float* out = (float*)d_out;
    const int B = in_sizes[0] / NFFT;   // 262144

    hipLaunchKernelGGL(init_w_kernel, dim3((WN * WK + BLOCK - 1) / BLOCK),
                       dim3(BLOCK), 0, stream);
    hipLaunchKernelGGL(dft_kernel, dim3(B / (TM * T)), dim3(BLOCK), 0, stream,
                       x, out, B);
}